// Round 6
// baseline (255.143 us; speedup 1.0000x reference)
//
#include <hip/hip_runtime.h>
#include <cstdint>
#include <cstddef>

// Problem: x += ssm_scan(rmsnorm(x,s1)); out = x + gelu(rmsnorm(x,s2)@w1+b1)@w2+b2
// B=4 L=2048 D=1024 N=16 DFF=4096, f32 in/out. bf16 MFMA for the MLP GEMMs.

#define BATCH 4
#define SEQLEN 2048
#define DMODEL 1024
#define NSTATE 16
#define DFF 4096
#define NCH 32     // chunks over L
#define LCH 64     // SEQLEN / NCH

typedef unsigned short ushort_t;
typedef __attribute__((ext_vector_type(8))) short short8;
typedef __attribute__((ext_vector_type(4))) float f32x4;

__device__ __forceinline__ ushort_t f2bf(float f) {
  uint32_t u = __builtin_bit_cast(uint32_t, f);
  uint32_t r = (u + 0x7FFFu + ((u >> 16) & 1u)) >> 16;
  return (ushort_t)r;
}

// ---------------- coefficient precompute ----------------
__global__ void coef_kernel(const float* __restrict__ A_ssm, const float* __restrict__ B_ssm,
                            const float* __restrict__ C_ssm,
                            float* __restrict__ dA_t, float* __restrict__ dBz_t,
                            float* __restrict__ dAc_t, float* __restrict__ Ct) {
  int d = blockIdx.x * 256 + threadIdx.x;
  if (d >= DMODEL) return;
  const float l0 = -6.907755278982137f;       // log(0.001)
  const float ld = 0.30701134573253947f;      // log(100)/15
  for (int n = 0; n < NSTATE; n++) {
    float dt = expf(l0 + (float)n * ld);
    float a  = A_ssm[d * NSTATE + n];
    float ea = expf(a);
    float da = expf(-ea * dt);
    float dbz = B_ssm[d * NSTATE + n] * (1.f - da) / ea;
    float dac = expf(-ea * dt * (float)LCH);
    dA_t [n * DMODEL + d] = da;
    dBz_t[n * DMODEL + d] = dbz;
    dAc_t[n * DMODEL + d] = dac;
    Ct   [n * DMODEL + d] = C_ssm[d * NSTATE + n];
  }
}

// ---------------- transpose f32 [R][C] -> bf16 [C][R] ----------------
__global__ void transpose_to_bf16(const float* __restrict__ src, ushort_t* __restrict__ dst,
                                  int R, int C) {
  __shared__ float tile[32][33];
  int bx = blockIdx.x * 32, by = blockIdx.y * 32;
  int tx = threadIdx.x, ty = threadIdx.y;
  #pragma unroll
  for (int i = 0; i < 4; i++) {
    int r = by + ty + i * 8;
    tile[ty + i * 8][tx] = src[(size_t)r * C + bx + tx];
  }
  __syncthreads();
  #pragma unroll
  for (int i = 0; i < 4; i++) {
    int c = bx + ty + i * 8;
    dst[(size_t)c * R + by + tx] = f2bf(tile[tx][ty + i * 8]);
  }
}

// ---------------- rmsnorm pass 1: rrms per row ----------------
__global__ void rms1_kernel(const float* __restrict__ x, float* __restrict__ rrms) {
  int row = blockIdx.x * 4 + (threadIdx.x >> 6);
  int lane = threadIdx.x & 63;
  const float4* p = (const float4*)(x + (size_t)row * DMODEL);
  float s = 0.f;
  #pragma unroll
  for (int w = 0; w < 4; w++) {
    float4 v = p[w * 64 + lane];
    s += v.x * v.x + v.y * v.y + v.z * v.z + v.w * v.w;
  }
  #pragma unroll
  for (int off = 32; off; off >>= 1) s += __shfl_xor(s, off, 64);
  if (lane == 0) rrms[row] = rsqrtf(s * (1.f / DMODEL) + 1e-6f);
}

// ---------------- scan pass1: per-chunk local final states ----------------
__global__ void scan_pass1(const float* __restrict__ x, const float* __restrict__ rrms,
                           const float* __restrict__ scale1,
                           const float* __restrict__ dA_t, const float* __restrict__ dBz_t,
                           float* __restrict__ s_fin) {
  int d = blockIdx.x * 256 + threadIdx.x;
  int b = blockIdx.y, c = blockIdx.z;
  float dA[NSTATE], dBz[NSTATE], s[NSTATE];
  #pragma unroll
  for (int n = 0; n < NSTATE; n++) {
    dA[n] = dA_t[n * DMODEL + d];
    dBz[n] = dBz_t[n * DMODEL + d];
    s[n] = 0.f;
  }
  float sc1 = scale1[d];
  const float* xp = x + ((size_t)b * SEQLEN + (size_t)c * LCH) * DMODEL + d;
  const float* rp = rrms + b * SEQLEN + c * LCH;
  for (int t = 0; t < LCH; t++) {
    float u = xp[(size_t)t * DMODEL] * rp[t] * sc1;
    #pragma unroll
    for (int n = 0; n < NSTATE; n++) s[n] = fmaf(s[n], dA[n], u * dBz[n]);
  }
  #pragma unroll
  for (int n = 0; n < NSTATE; n++)
    s_fin[(((size_t)n * BATCH + b) * NCH + c) * DMODEL + d] = s[n];
}

// ---------------- scan pass2: serial chunk-carry combine ----------------
__global__ void scan_pass2(const float* __restrict__ s_fin, const float* __restrict__ dAc_t,
                           float* __restrict__ s_in) {
  int idx = blockIdx.x * 256 + threadIdx.x;  // BATCH*DMODEL*NSTATE = 65536
  int d = idx & (DMODEL - 1);
  int b = (idx >> 10) & (BATCH - 1);
  int n = idx >> 12;
  float dc = dAc_t[n * DMODEL + d];
  float s = 0.f;
  for (int c = 0; c < NCH; c++) {
    size_t o = (((size_t)n * BATCH + b) * NCH + c) * DMODEL + d;
    s_in[o] = s;
    s = s_fin[o] + dc * s;
  }
}

// ---------------- scan pass3: full scan with carry-in, write x2 = x + y + u*D ----------------
__global__ void scan_pass3(const float* __restrict__ x, const float* __restrict__ rrms,
                           const float* __restrict__ scale1,
                           const float* __restrict__ dA_t, const float* __restrict__ dBz_t,
                           const float* __restrict__ Ct, const float* __restrict__ Dv,
                           const float* __restrict__ s_in, float* __restrict__ out) {
  int d = blockIdx.x * 256 + threadIdx.x;
  int b = blockIdx.y, c = blockIdx.z;
  float dA[NSTATE], dBz[NSTATE], Cc[NSTATE], s[NSTATE];
  #pragma unroll
  for (int n = 0; n < NSTATE; n++) {
    dA[n] = dA_t[n * DMODEL + d];
    dBz[n] = dBz_t[n * DMODEL + d];
    Cc[n] = Ct[n * DMODEL + d];
    s[n] = s_in[(((size_t)n * BATCH + b) * NCH + c) * DMODEL + d];
  }
  float sc1 = scale1[d], Dd = Dv[d];
  const float* xp = x + ((size_t)b * SEQLEN + (size_t)c * LCH) * DMODEL + d;
  const float* rp = rrms + b * SEQLEN + c * LCH;
  float* op = out + ((size_t)b * SEQLEN + (size_t)c * LCH) * DMODEL + d;
  for (int t = 0; t < LCH; t++) {
    float xv = xp[(size_t)t * DMODEL];
    float u = xv * rp[t] * sc1;
    float y = 0.f;
    #pragma unroll
    for (int n = 0; n < NSTATE; n++) {
      s[n] = fmaf(s[n], dA[n], u * dBz[n]);
      y = fmaf(Cc[n], s[n], y);
    }
    op[(size_t)t * DMODEL] = xv + y + u * Dd;
  }
}

// ---------------- rmsnorm2: x2 -> bf16 normalized ----------------
__global__ void rms2_kernel(const float* __restrict__ x2, const float* __restrict__ scale2,
                            ushort_t* __restrict__ hb) {
  int row = blockIdx.x * 4 + (threadIdx.x >> 6);
  int lane = threadIdx.x & 63;
  const float4* p = (const float4*)(x2 + (size_t)row * DMODEL);
  float4 v[4];
  float s = 0.f;
  #pragma unroll
  for (int w = 0; w < 4; w++) {
    v[w] = p[w * 64 + lane];
    s += v[w].x * v[w].x + v[w].y * v[w].y + v[w].z * v[w].z + v[w].w * v[w].w;
  }
  #pragma unroll
  for (int off = 32; off; off >>= 1) s += __shfl_xor(s, off, 64);
  float r = rsqrtf(s * (1.f / DMODEL) + 1e-6f);
  const float4* sc = (const float4*)scale2;
  #pragma unroll
  for (int w = 0; w < 4; w++) {
    float4 scv = sc[w * 64 + lane];
    ushort4 u;
    u.x = f2bf(v[w].x * r * scv.x);
    u.y = f2bf(v[w].y * r * scv.y);
    u.z = f2bf(v[w].z * r * scv.z);
    u.w = f2bf(v[w].w * r * scv.w);
    *(ushort4*)(hb + (size_t)row * DMODEL + (size_t)(w * 64 + lane) * 4) = u;
  }
}

// ====== 128x128 / 4-wave / 3-slot circular GEMM, 1 barrier + 1 counted fence per tile ======
// C[M][N] = A[M][K] * B[N][K]^T, bf16 in, f32 acc.
// 48 KB LDS -> 3 blocks/CU (TLP does the pipelining, m114/m97); 0 bank conflicts (r3 swizzle).
// Per tile t: {8x ds_read(slot t%3); stage(t+2 -> slot (t+2)%3); setprio; 16 MFMA; setprio;
//              fence vmcnt(LPT); s_barrier}.
// Safety: slot (t+2)%3 == slot of t-1, readers passed end-of-(t-1) barrier. fence<LPT>+bar
// publishes tile t+1 before iter t+1's reads. MFMA issue implies its ds_reads completed.
// Prologue fence+bar establishes tile-0 (r4 lesson).

#define BKG 32

template <int N>
__device__ __forceinline__ void fence_vm() {
  asm volatile("s_waitcnt vmcnt(%0)" :: "n"(N) : "memory");
}

__device__ __forceinline__ void bar() { asm volatile("s_barrier" ::: "memory"); }

__device__ __forceinline__ void gl2lds16(const ushort_t* g, ushort_t* l) {
  __builtin_amdgcn_global_load_lds(
      (const __attribute__((address_space(1))) unsigned int*)g,
      (__attribute__((address_space(3))) unsigned int*)l, 16, 0, 0);
}

// MODE 1: out = bf16(gelu(acc + bias))   (out is ushort_t*)
// MODE 2: out = resid + acc + bias       (out is float*)
template <int MODE, int K>
__global__ __launch_bounds__(256) void gemm_cv(const ushort_t* __restrict__ A,
                                               const ushort_t* __restrict__ B,
                                               const float* __restrict__ bias,
                                               const float* __restrict__ resid,
                                               void* __restrict__ outp,
                                               int M, int N) {
  constexpr int BM = 128, BN = 128;
  constexpr int TILEA = BM * BKG;           // 4096 elems (8 KB)
  constexpr int SLOT  = TILEA * 2;          // A + B, 16 KB
  constexpr int LPT   = 4;                  // gl2lds per thread per tile (2 A + 2 B)
  constexpr int NT    = K / BKG;
  __shared__ __align__(16) ushort_t lds[3 * SLOT];   // 48 KB

  const int tid = threadIdx.x;
  const int wave = tid >> 6, lane = tid & 63;
  const int wr = wave >> 1, wc = wave & 1;

  // XCD-aware bijective swizzle (nwg % 8 == 0 for both GEMMs)
  const int nwg = gridDim.x;
  const int cpx = nwg >> 3;
  const int bid = blockIdx.x;
  const int wg  = (bid & 7) * cpx + (bid >> 3);
  const int nbn = N / BN;
  const int m0 = (wg / nbn) * BM;
  const int n0 = (wg % nbn) * BN;

  // staging: thread tid -> LDS row tid>>2 (+64 per j), 16B chunk (tid&3).
  // Global source column pre-swizzled; reads XOR it back (0 conflicts, verified r3).
  const int scol = 8 * ((tid & 3) ^ ((tid >> 3) & 3));
  const ushort_t* aB = A + (size_t)(m0 + (tid >> 2)) * K + scol;
  const ushort_t* bB = B + (size_t)(n0 + (tid >> 2)) * K + scol;
  const int waveOff = wave * 512;           // elems (64 lanes x 8)

  auto stage = [&](int slot, int t) {
    ushort_t* sA = lds + slot * SLOT;
    ushort_t* sB = sA + TILEA;
    #pragma unroll
    for (int j = 0; j < 2; j++)
      gl2lds16(aB + (size_t)t * BKG + (size_t)j * 64 * K, sA + j * 2048 + waveOff);
    #pragma unroll
    for (int j = 0; j < 2; j++)
      gl2lds16(bB + (size_t)t * BKG + (size_t)j * 64 * K, sB + j * 2048 + waveOff);
  };

  f32x4 acc[4][4] = {};

  stage(0, 0); stage(1, 1);
  fence_vm<LPT>();   // tile 0 landed (this thread); bar publishes all threads
  bar();

  const int r = lane & 15;
  const int cswz = ((lane >> 4) * 8) ^ (((r >> 1) & 3) << 3);   // swizzled read column

  int s0 = 0;  // slot of current tile
  for (int t = 0; t < NT; ++t) {
    const ushort_t* sA = lds + s0 * SLOT;
    const ushort_t* sB = sA + TILEA;

    short8 bfr[4], af[4];
    #pragma unroll
    for (int n = 0; n < 4; n++)
      bfr[n] = *(const short8*)(sB + (size_t)(wc * 64 + n * 16 + r) * BKG + cswz);
    #pragma unroll
    for (int m = 0; m < 4; m++)
      af[m] = *(const short8*)(sA + (size_t)(wr * 64 + m * 16 + r) * BKG + cswz);

    if (t + 2 < NT) {
      int s2 = s0 + 2; if (s2 >= 3) s2 -= 3;
      stage(s2, t + 2);
    }

    __builtin_amdgcn_s_setprio(1);
    #pragma unroll
    for (int m = 0; m < 4; m++)
      #pragma unroll
      for (int n = 0; n < 4; n++)
        acc[m][n] = __builtin_amdgcn_mfma_f32_16x16x32_bf16(af[m], bfr[n], acc[m][n], 0, 0, 0);
    __builtin_amdgcn_s_setprio(0);

    if (t + 2 < NT) fence_vm<LPT>();   // tile t+1 landed; t+2 in flight
    else            fence_vm<0>();     // tail: drain
    bar();

    s0 = (s0 == 2) ? 0 : s0 + 1;
  }

  // epilogue
  const int colb = n0 + wc * 64 + r;
  const int rowb = m0 + wr * 64 + ((lane >> 4) << 2);
  #pragma unroll
  for (int n = 0; n < 4; n++) {
    int col = colb + n * 16;
    float bs = bias[col];
    #pragma unroll
    for (int m = 0; m < 4; m++) {
      int row = rowb + m * 16;
      #pragma unroll
      for (int j = 0; j < 4; j++) {
        float v = acc[m][n][j] + bs;
        size_t o = (size_t)(row + j) * N + col;
        if (MODE == 1) {
          float g = 0.5f * v * (1.f + erff(v * 0.70710678118654752f));
          ((ushort_t*)outp)[o] = f2bf(g);
        } else {
          ((float*)outp)[o] = resid[o] + v;
        }
      }
    }
  }
}

// ---------------- launch ----------------
extern "C" void kernel_launch(void* const* d_in, const int* in_sizes, int n_in,
                              void* d_out, int out_size, void* d_ws, size_t ws_size,
                              hipStream_t stream) {
  (void)in_sizes; (void)n_in; (void)out_size; (void)ws_size;
  const float* x      = (const float*)d_in[0];
  const float* A_ssm  = (const float*)d_in[1];
  const float* B_ssm  = (const float*)d_in[2];
  const float* C_ssm  = (const float*)d_in[3];
  const float* D_ssm  = (const float*)d_in[4];
  const float* scale1 = (const float*)d_in[5];
  const float* scale2 = (const float*)d_in[6];
  const float* w1     = (const float*)d_in[7];
  const float* b1     = (const float*)d_in[8];
  const float* w2     = (const float*)d_in[9];
  const float* b2     = (const float*)d_in[10];
  float* out = (float*)d_out;

  char* ws = (char*)d_ws;
  float*    rrms  = (float*)(ws + 0);                         // 32 KB
  float*    dA_t  = (float*)(ws + 32768);                     // 64 KB
  float*    dBz_t = (float*)(ws + 98304);                     // 64 KB
  float*    dAc_t = (float*)(ws + 163840);                    // 64 KB
  float*    Ct    = (float*)(ws + 229376);                    // 64 KB
  float*    s_fin = (float*)(ws + 294912);                    // 8 MB
  float*    s_in  = (float*)(ws + 8683520);                   // 8 MB
  ushort_t* hb    = (ushort_t*)(ws + 17072128);               // 16 MB
  ushort_t* w1t   = (ushort_t*)(ws + 33849344);               // 8 MB
  ushort_t* w2t   = (ushort_t*)(ws + 42237952);               // 8 MB
  ushort_t* gb    = (ushort_t*)(ws + 50626560);               // 64 MB

  const int ROWS = BATCH * SEQLEN;  // 8192

  coef_kernel<<<DMODEL / 256, 256, 0, stream>>>(A_ssm, B_ssm, C_ssm, dA_t, dBz_t, dAc_t, Ct);
  transpose_to_bf16<<<dim3(DFF / 32, DMODEL / 32), dim3(32, 8), 0, stream>>>(w1, w1t, DMODEL, DFF);
  transpose_to_bf16<<<dim3(DMODEL / 32, DFF / 32), dim3(32, 8), 0, stream>>>(w2, w2t, DFF, DMODEL);
  rms1_kernel<<<ROWS / 4, 256, 0, stream>>>(x, rrms);
  scan_pass1<<<dim3(DMODEL / 256, BATCH, NCH), 256, 0, stream>>>(x, rrms, scale1, dA_t, dBz_t, s_fin);
  scan_pass2<<<(BATCH * DMODEL * NSTATE) / 256, 256, 0, stream>>>(s_fin, dAc_t, s_in);
  scan_pass3<<<dim3(DMODEL / 256, BATCH, NCH), 256, 0, stream>>>(x, rrms, scale1, dA_t, dBz_t, Ct,
                                                                 D_ssm, s_in, out);
  rms2_kernel<<<ROWS / 4, 256, 0, stream>>>(out, scale2, hb);

  // gemm1: [8192x1024] @ [1024x4096] -> gelu -> gb (bf16).  2048 blocks, 128x128 tile.
  gemm_cv<1, DMODEL><<<(ROWS / 128) * (DFF / 128), 256, 0, stream>>>(
      hb, w1t, b1, nullptr, gb, ROWS, DFF);
  // gemm2: [8192x4096] @ [4096x1024] + resid -> out (f32). 512 blocks, 128x128 tile.
  gemm_cv<2, DFF><<<(ROWS / 128) * (DMODEL / 128), 256, 0, stream>>>(
      gb, w2t, b2, out, out, ROWS, DMODEL);
}

// Round 7
// 237.638 us; speedup vs baseline: 1.0737x; 1.0737x over previous
//
#include <hip/hip_runtime.h>
#include <cstdint>
#include <cstddef>

// Problem: x += ssm_scan(rmsnorm(x,s1)); out = x + gelu(rmsnorm(x,s2)@w1+b1)@w2+b2
// B=4 L=2048 D=1024 N=16 DFF=4096, f32 in/out. bf16 MFMA for the MLP GEMMs.

#define BATCH 4
#define SEQLEN 2048
#define DMODEL 1024
#define NSTATE 16
#define DFF 4096
#define NCH 32     // chunks over L
#define LCH 64     // SEQLEN / NCH

typedef unsigned short ushort_t;
typedef __attribute__((ext_vector_type(8))) short short8;
typedef __attribute__((ext_vector_type(4))) float f32x4;

__device__ __forceinline__ ushort_t f2bf(float f) {
  uint32_t u = __builtin_bit_cast(uint32_t, f);
  uint32_t r = (u + 0x7FFFu + ((u >> 16) & 1u)) >> 16;
  return (ushort_t)r;
}

// ---------------- coefficient precompute ----------------
__global__ void coef_kernel(const float* __restrict__ A_ssm, const float* __restrict__ B_ssm,
                            const float* __restrict__ C_ssm,
                            float* __restrict__ dA_t, float* __restrict__ dBz_t,
                            float* __restrict__ dAc_t, float* __restrict__ Ct) {
  int d = blockIdx.x * 256 + threadIdx.x;
  if (d >= DMODEL) return;
  const float l0 = -6.907755278982137f;       // log(0.001)
  const float ld = 0.30701134573253947f;      // log(100)/15
  for (int n = 0; n < NSTATE; n++) {
    float dt = expf(l0 + (float)n * ld);
    float a  = A_ssm[d * NSTATE + n];
    float ea = expf(a);
    float da = expf(-ea * dt);
    float dbz = B_ssm[d * NSTATE + n] * (1.f - da) / ea;
    float dac = expf(-ea * dt * (float)LCH);
    dA_t [n * DMODEL + d] = da;
    dBz_t[n * DMODEL + d] = dbz;
    dAc_t[n * DMODEL + d] = dac;
    Ct   [n * DMODEL + d] = C_ssm[d * NSTATE + n];
  }
}

// ---------------- transpose f32 [R][C] -> bf16 [C][R] ----------------
__global__ void transpose_to_bf16(const float* __restrict__ src, ushort_t* __restrict__ dst,
                                  int R, int C) {
  __shared__ float tile[32][33];
  int bx = blockIdx.x * 32, by = blockIdx.y * 32;
  int tx = threadIdx.x, ty = threadIdx.y;
  #pragma unroll
  for (int i = 0; i < 4; i++) {
    int r = by + ty + i * 8;
    tile[ty + i * 8][tx] = src[(size_t)r * C + bx + tx];
  }
  __syncthreads();
  #pragma unroll
  for (int i = 0; i < 4; i++) {
    int c = bx + ty + i * 8;
    dst[(size_t)c * R + by + tx] = f2bf(tile[tx][ty + i * 8]);
  }
}

// ---------------- rmsnorm pass 1: rrms per row ----------------
__global__ void rms1_kernel(const float* __restrict__ x, float* __restrict__ rrms) {
  int row = blockIdx.x * 4 + (threadIdx.x >> 6);
  int lane = threadIdx.x & 63;
  const float4* p = (const float4*)(x + (size_t)row * DMODEL);
  float s = 0.f;
  #pragma unroll
  for (int w = 0; w < 4; w++) {
    float4 v = p[w * 64 + lane];
    s += v.x * v.x + v.y * v.y + v.z * v.z + v.w * v.w;
  }
  #pragma unroll
  for (int off = 32; off; off >>= 1) s += __shfl_xor(s, off, 64);
  if (lane == 0) rrms[row] = rsqrtf(s * (1.f / DMODEL) + 1e-6f);
}

// ---------------- scan pass1: per-chunk local final states ----------------
__global__ void scan_pass1(const float* __restrict__ x, const float* __restrict__ rrms,
                           const float* __restrict__ scale1,
                           const float* __restrict__ dA_t, const float* __restrict__ dBz_t,
                           float* __restrict__ s_fin) {
  int d = blockIdx.x * 256 + threadIdx.x;
  int b = blockIdx.y, c = blockIdx.z;
  float dA[NSTATE], dBz[NSTATE], s[NSTATE];
  #pragma unroll
  for (int n = 0; n < NSTATE; n++) {
    dA[n] = dA_t[n * DMODEL + d];
    dBz[n] = dBz_t[n * DMODEL + d];
    s[n] = 0.f;
  }
  float sc1 = scale1[d];
  const float* xp = x + ((size_t)b * SEQLEN + (size_t)c * LCH) * DMODEL + d;
  const float* rp = rrms + b * SEQLEN + c * LCH;
  for (int t = 0; t < LCH; t++) {
    float u = xp[(size_t)t * DMODEL] * rp[t] * sc1;
    #pragma unroll
    for (int n = 0; n < NSTATE; n++) s[n] = fmaf(s[n], dA[n], u * dBz[n]);
  }
  #pragma unroll
  for (int n = 0; n < NSTATE; n++)
    s_fin[(((size_t)n * BATCH + b) * NCH + c) * DMODEL + d] = s[n];
}

// ---------------- scan pass2: serial chunk-carry combine ----------------
__global__ void scan_pass2(const float* __restrict__ s_fin, const float* __restrict__ dAc_t,
                           float* __restrict__ s_in) {
  int idx = blockIdx.x * 256 + threadIdx.x;  // BATCH*DMODEL*NSTATE = 65536
  int d = idx & (DMODEL - 1);
  int b = (idx >> 10) & (BATCH - 1);
  int n = idx >> 12;
  float dc = dAc_t[n * DMODEL + d];
  float s = 0.f;
  for (int c = 0; c < NCH; c++) {
    size_t o = (((size_t)n * BATCH + b) * NCH + c) * DMODEL + d;
    s_in[o] = s;
    s = s_fin[o] + dc * s;
  }
}

// ---------------- scan pass3: full scan with carry-in, write x2 = x + y + u*D ----------------
__global__ void scan_pass3(const float* __restrict__ x, const float* __restrict__ rrms,
                           const float* __restrict__ scale1,
                           const float* __restrict__ dA_t, const float* __restrict__ dBz_t,
                           const float* __restrict__ Ct, const float* __restrict__ Dv,
                           const float* __restrict__ s_in, float* __restrict__ out) {
  int d = blockIdx.x * 256 + threadIdx.x;
  int b = blockIdx.y, c = blockIdx.z;
  float dA[NSTATE], dBz[NSTATE], Cc[NSTATE], s[NSTATE];
  #pragma unroll
  for (int n = 0; n < NSTATE; n++) {
    dA[n] = dA_t[n * DMODEL + d];
    dBz[n] = dBz_t[n * DMODEL + d];
    Cc[n] = Ct[n * DMODEL + d];
    s[n] = s_in[(((size_t)n * BATCH + b) * NCH + c) * DMODEL + d];
  }
  float sc1 = scale1[d], Dd = Dv[d];
  const float* xp = x + ((size_t)b * SEQLEN + (size_t)c * LCH) * DMODEL + d;
  const float* rp = rrms + b * SEQLEN + c * LCH;
  float* op = out + ((size_t)b * SEQLEN + (size_t)c * LCH) * DMODEL + d;
  for (int t = 0; t < LCH; t++) {
    float xv = xp[(size_t)t * DMODEL];
    float u = xv * rp[t] * sc1;
    float y = 0.f;
    #pragma unroll
    for (int n = 0; n < NSTATE; n++) {
      s[n] = fmaf(s[n], dA[n], u * dBz[n]);
      y = fmaf(Cc[n], s[n], y);
    }
    op[(size_t)t * DMODEL] = xv + y + u * Dd;
  }
}

// ---------------- rmsnorm2: x2 -> bf16 normalized ----------------
__global__ void rms2_kernel(const float* __restrict__ x2, const float* __restrict__ scale2,
                            ushort_t* __restrict__ hb) {
  int row = blockIdx.x * 4 + (threadIdx.x >> 6);
  int lane = threadIdx.x & 63;
  const float4* p = (const float4*)(x2 + (size_t)row * DMODEL);
  float4 v[4];
  float s = 0.f;
  #pragma unroll
  for (int w = 0; w < 4; w++) {
    v[w] = p[w * 64 + lane];
    s += v[w].x * v[w].x + v[w].y * v[w].y + v[w].z * v[w].z + v[w].w * v[w].w;
  }
  #pragma unroll
  for (int off = 32; off; off >>= 1) s += __shfl_xor(s, off, 64);
  float r = rsqrtf(s * (1.f / DMODEL) + 1e-6f);
  const float4* sc = (const float4*)scale2;
  #pragma unroll
  for (int w = 0; w < 4; w++) {
    float4 scv = sc[w * 64 + lane];
    ushort4 u;
    u.x = f2bf(v[w].x * r * scv.x);
    u.y = f2bf(v[w].y * r * scv.y);
    u.z = f2bf(v[w].z * r * scv.z);
    u.w = f2bf(v[w].w * r * scv.w);
    *(ushort4*)(hb + (size_t)row * DMODEL + (size_t)(w * 64 + lane) * 4) = u;
  }
}

// ====== 256-wide / 8-wave / 4-slot circular GEMM, 1 barrier + 1 counted fence per tile ======
// C[M][N] = A[M][K] * B[N][K]^T, bf16 in, f32 acc.
// 256-tall tiles halve LDS-read and HBM bytes per FLOP vs 128^2 (per block-ktile:
// matrix 1241cy >> LDS 500cy -> LDS pipe no longer caps MfmaUtil).
// Per tile t: {12x ds_read(slot t&3); stage(t+3 -> slot (t-1)&3); setprio; MFMA xMR*NR
//  (compiler interleaves lgkm waits); setprio; counted fence; s_barrier}.
// Safety: reaching bar_{t-1} required MFMA(t-1) issue which required slot(t-1) reads
// complete -> stage into slot (t-1)&3 after bar_{t-1} is race-free. Counted fence
// (never 0 until tail) + bar publishes tile t+1 before iter t+1 reads it. Prologue
// fence+bar establishes tile 0 (r4 lesson). Swizzle: linear LDS dest + pre-swizzled
// global source col + XOR'd read col (0 bank conflicts, verified r3/r5/r6).

#define BKG 32

template <int N>
__device__ __forceinline__ void fence_vm() {
  asm volatile("s_waitcnt vmcnt(%0)" :: "n"(N) : "memory");
}

__device__ __forceinline__ void bar() { asm volatile("s_barrier" ::: "memory"); }

__device__ __forceinline__ void gl2lds16(const ushort_t* g, ushort_t* l) {
  __builtin_amdgcn_global_load_lds(
      (const __attribute__((address_space(1))) unsigned int*)g,
      (__attribute__((address_space(3))) unsigned int*)l, 16, 0, 0);
}

// MODE 1: out = bf16(gelu(acc + bias))   (out is ushort_t*)
// MODE 2: out = resid + acc + bias       (out is float*)
template <int BM, int BN, int WM, int WN, int MODE, int K>
__global__ __launch_bounds__(512) void gemm_cv(const ushort_t* __restrict__ A,
                                               const ushort_t* __restrict__ B,
                                               const float* __restrict__ bias,
                                               const float* __restrict__ resid,
                                               void* __restrict__ outp,
                                               int M, int N) {
  constexpr int TILEA = BM * BKG;
  constexpr int TILEB = BN * BKG;
  constexpr int SLOT  = TILEA + TILEB;
  constexpr int NA = BM / 128;              // gl2lds per thread, A (512 threads)
  constexpr int NB = BN / 128;
  constexpr int LPT = NA + NB;
  constexpr int MR = BM / (WM * 16);
  constexpr int NR = BN / (WN * 16);
  constexpr int NT = K / BKG;
  __shared__ __align__(16) ushort_t lds[4 * SLOT];

  const int tid = threadIdx.x;
  const int wave = tid >> 6, lane = tid & 63;
  const int wr = wave / WN, wc = wave % WN;

  // XCD-aware bijective swizzle (nwg % 8 == 0 for both GEMMs)
  const int nwg = gridDim.x;
  const int cpx = nwg >> 3;
  const int bid = blockIdx.x;
  const int wg  = (bid & 7) * cpx + (bid >> 3);
  const int nbn = N / BN;
  const int m0 = (wg / nbn) * BM;
  const int n0 = (wg % nbn) * BN;

  // staging: thread tid -> LDS row tid>>2 within each 128-row group, 16B chunk (tid&3).
  // Global source column pre-swizzled; reads XOR it back (0 conflicts, verified r3).
  const int scol = 8 * ((tid & 3) ^ ((tid >> 3) & 3));
  const ushort_t* aB = A + (size_t)(m0 + (tid >> 2)) * K + scol;
  const ushort_t* bB = B + (size_t)(n0 + (tid >> 2)) * K + scol;
  const int waveOff = wave * 512;           // elems (64 lanes x 8)

  auto stage = [&](int slot, int t) {
    ushort_t* sA = lds + slot * SLOT;
    ushort_t* sB = sA + TILEA;
    #pragma unroll
    for (int j = 0; j < NA; j++)
      gl2lds16(aB + (size_t)t * BKG + (size_t)j * 128 * K, sA + j * 4096 + waveOff);
    #pragma unroll
    for (int j = 0; j < NB; j++)
      gl2lds16(bB + (size_t)t * BKG + (size_t)j * 128 * K, sB + j * 4096 + waveOff);
  };

  f32x4 acc[MR][NR] = {};

  stage(0, 0); stage(1, 1); stage(2, 2);
  fence_vm<2 * LPT>();   // tile 0 landed (this thread); bar publishes all threads
  bar();

  const int r = lane & 15;
  const int cswz = ((lane >> 4) * 8) ^ (((r >> 1) & 3) << 3);   // swizzled read column

  #pragma unroll 2
  for (int t = 0; t < NT; ++t) {
    const ushort_t* sA = lds + (t & 3) * SLOT;
    const ushort_t* sB = sA + TILEA;

    short8 bfr[NR], af[MR];
    #pragma unroll
    for (int n = 0; n < NR; n++)
      bfr[n] = *(const short8*)(sB + (size_t)(wc * (BN / WN) + n * 16 + r) * BKG + cswz);
    #pragma unroll
    for (int m = 0; m < MR; m++)
      af[m] = *(const short8*)(sA + (size_t)(wr * (BM / WM) + m * 16 + r) * BKG + cswz);

    if (t + 3 < NT) stage((t + 3) & 3, t + 3);

    __builtin_amdgcn_s_setprio(1);
    #pragma unroll
    for (int m = 0; m < MR; m++)
      #pragma unroll
      for (int n = 0; n < NR; n++)
        acc[m][n] = __builtin_amdgcn_mfma_f32_16x16x32_bf16(af[m], bfr[n], acc[m][n], 0, 0, 0);
    __builtin_amdgcn_s_setprio(0);

    if (t + 3 < NT)      fence_vm<2 * LPT>();   // tile t+1 landed; t+2,t+3 in flight
    else if (t + 2 < NT) fence_vm<LPT>();
    else                 fence_vm<0>();
    bar();
  }

  // epilogue
  const int colb = n0 + wc * (BN / WN) + r;
  const int rowb = m0 + wr * (BM / WM) + ((lane >> 4) << 2);
  #pragma unroll
  for (int n = 0; n < NR; n++) {
    int col = colb + n * 16;
    float bs = bias[col];
    #pragma unroll
    for (int m = 0; m < MR; m++) {
      int row = rowb + m * 16;
      #pragma unroll
      for (int j = 0; j < 4; j++) {
        float v = acc[m][n][j] + bs;
        size_t o = (size_t)(row + j) * N + col;
        if (MODE == 1) {
          float g = 0.5f * v * (1.f + erff(v * 0.70710678118654752f));
          ((ushort_t*)outp)[o] = f2bf(g);
        } else {
          ((float*)outp)[o] = resid[o] + v;
        }
      }
    }
  }
}

// ---------------- launch ----------------
extern "C" void kernel_launch(void* const* d_in, const int* in_sizes, int n_in,
                              void* d_out, int out_size, void* d_ws, size_t ws_size,
                              hipStream_t stream) {
  (void)in_sizes; (void)n_in; (void)out_size; (void)ws_size;
  const float* x      = (const float*)d_in[0];
  const float* A_ssm  = (const float*)d_in[1];
  const float* B_ssm  = (const float*)d_in[2];
  const float* C_ssm  = (const float*)d_in[3];
  const float* D_ssm  = (const float*)d_in[4];
  const float* scale1 = (const float*)d_in[5];
  const float* scale2 = (const float*)d_in[6];
  const float* w1     = (const float*)d_in[7];
  const float* b1     = (const float*)d_in[8];
  const float* w2     = (const float*)d_in[9];
  const float* b2     = (const float*)d_in[10];
  float* out = (float*)d_out;

  char* ws = (char*)d_ws;
  float*    rrms  = (float*)(ws + 0);                         // 32 KB
  float*    dA_t  = (float*)(ws + 32768);                     // 64 KB
  float*    dBz_t = (float*)(ws + 98304);                     // 64 KB
  float*    dAc_t = (float*)(ws + 163840);                    // 64 KB
  float*    Ct    = (float*)(ws + 229376);                    // 64 KB
  float*    s_fin = (float*)(ws + 294912);                    // 8 MB
  float*    s_in  = (float*)(ws + 8683520);                   // 8 MB
  ushort_t* hb    = (ushort_t*)(ws + 17072128);               // 16 MB
  ushort_t* w1t   = (ushort_t*)(ws + 33849344);               // 8 MB
  ushort_t* w2t   = (ushort_t*)(ws + 42237952);               // 8 MB
  ushort_t* gb    = (ushort_t*)(ws + 50626560);               // 64 MB

  const int ROWS = BATCH * SEQLEN;  // 8192

  coef_kernel<<<DMODEL / 256, 256, 0, stream>>>(A_ssm, B_ssm, C_ssm, dA_t, dBz_t, dAc_t, Ct);
  transpose_to_bf16<<<dim3(DFF / 32, DMODEL / 32), dim3(32, 8), 0, stream>>>(w1, w1t, DMODEL, DFF);
  transpose_to_bf16<<<dim3(DMODEL / 32, DFF / 32), dim3(32, 8), 0, stream>>>(w2, w2t, DFF, DMODEL);
  rms1_kernel<<<ROWS / 4, 256, 0, stream>>>(x, rrms);
  scan_pass1<<<dim3(DMODEL / 256, BATCH, NCH), 256, 0, stream>>>(x, rrms, scale1, dA_t, dBz_t, s_fin);
  scan_pass2<<<(BATCH * DMODEL * NSTATE) / 256, 256, 0, stream>>>(s_fin, dAc_t, s_in);
  scan_pass3<<<dim3(DMODEL / 256, BATCH, NCH), 256, 0, stream>>>(x, rrms, scale1, dA_t, dBz_t, Ct,
                                                                 D_ssm, s_in, out);
  rms2_kernel<<<ROWS / 4, 256, 0, stream>>>(out, scale2, hb);

  // gemm1: [8192x1024] @ [1024x4096] -> gelu -> gb (bf16).  512 blocks, 256x256 tile.
  gemm_cv<256, 256, 2, 4, 1, DMODEL><<<(ROWS / 256) * (DFF / 256), 512, 0, stream>>>(
      hb, w1t, b1, nullptr, gb, ROWS, DFF);
  // gemm2: [8192x4096] @ [4096x1024] + resid -> out (f32). 256 blocks, 256x128 tile.
  gemm_cv<256, 128, 4, 2, 2, DFF><<<(ROWS / 256) * (DMODEL / 128), 512, 0, stream>>>(
      gb, w2t, b2, out, out, ROWS, DMODEL);
}